// Round 9
// baseline (919.922 us; speedup 1.0000x reference)
//
#include <hip/hip_runtime.h>
#include <hip/hip_bf16.h>

typedef __attribute__((ext_vector_type(8))) short bf16x8;
typedef __attribute__((ext_vector_type(4))) float f32x4;
typedef __attribute__((ext_vector_type(4))) unsigned short u16x4;
typedef unsigned short u16;

#define BATCH 100000
#define EPE 200000
#define NBLK 1024

// ---- workspace layout (bytes), peak ~27.3 MB ----
#define OFF_AP    ((size_t)0)          // u16 [1024*1024]
#define OFF_ATP   ((size_t)2097152)    // u16 [1024*1024]
#define OFF_SP    ((size_t)4194304)    // u16 [1024*1024]
#define OFF_T1    ((size_t)6291456)    // u16 [2048*2048] (dead after phase C1)
#define OFF_G     ((size_t)6291456)    // f32 [1024*1024] (reuses T1 space AFTER C1 barrier)
#define OFF_GT    ((size_t)10485760)   // f32 [1024*1024]
#define OFF_GNS   ((size_t)14680064)   // u16 [1024*1024]
#define OFF_GNDT  ((size_t)16777216)   // u16 [1024*1024]
#define OFF_W1AT  ((size_t)18874368)   // u16 [256*1024]
#define OFF_W1BT  ((size_t)19398656)   // u16 [256*1024]
#define OFF_W2T   ((size_t)19922944)   // u16 [128*256]
#define OFF_HID   ((size_t)19988480)   // u16 [2048*256]
#define OFF_NEP   ((size_t)21037056)   // u16 [2048*128]
#define OFF_CEP   ((size_t)21561344)   // u16 [2048*128]
#define OFF_HSRC  ((size_t)22085632)   // u16 [1024*256]
#define OFF_HDST  ((size_t)22609920)   // u16 [1024*256]
#define OFF_T2    ((size_t)23134208)   // f32 [1024*1024]
#define OFF_DEGS  ((size_t)27328512)   // f32 [1024]
#define OFF_DEGD  ((size_t)27332608)   // f32 [1024]
#define OFF_PART  ((size_t)27336704)   // f32 [391]
#define OFF_BAR   ((size_t)27340800)   // int [16] barrier counter (memset to 0 each call)

__device__ __forceinline__ u16 f2b(float f) {
  union { float f; unsigned u; } v; v.f = f;
  unsigned r = v.u + 0x7fffu + ((v.u >> 16) & 1u);
  return (u16)(r >> 16);
}
__device__ __forceinline__ float b2f(u16 h) {
  union { unsigned u; float f; } v; v.u = ((unsigned)h) << 16;
  return v.f;
}

#define AS1C(p) ((const __attribute__((address_space(1))) void*)(p))
#define AS3(p)  ((__attribute__((address_space(3))) void*)(p))

// ---------------- grid barrier: release add, RELAXED poll (no cache inv), one acquire fence ----
__device__ __forceinline__ void gbar(int* bar, int phase) {
  __syncthreads();
  if (threadIdx.x == 0) {
    __hip_atomic_fetch_add(bar, 1, __ATOMIC_RELEASE, __HIP_MEMORY_SCOPE_SYSTEM);
    const int target = phase * (int)gridDim.x;
    while (__hip_atomic_load(bar, __ATOMIC_RELAXED, __HIP_MEMORY_SCOPE_SYSTEM) < target)
      __builtin_amdgcn_s_sleep(4);
  }
  __syncthreads();
  __builtin_amdgcn_fence(__ATOMIC_ACQUIRE, "agent");   // one L1/L2 inv per wave per phase
}

// ---------------- 32x32-tile bf16 MFMA core, 2-phase dbuf, XOR-swizzled LDS ----------------
// LDS slot (row, c) holds global k-chunk (c ^ (row&7)); ds_read applies same XOR ->
// 16B reads spread across all 32 banks (2 lanes/bank aliasing = free).
__device__ __forceinline__ f32x4 gemm_core32(const u16* A, const u16* BT,
    int K, int lda, int ldbt, int brow, int bcol, u16* As, u16* Bs) {
  const int t = threadIdx.x;
  const int w = t >> 6, lane = t & 63;
  const int wr = w >> 1, wc = w & 1;
  const int r16 = lane & 15, kg = lane >> 4;
  const int row = t >> 3;
  const int csrc = (t & 7) ^ (row & 7);          // pre-swizzled source chunk
  f32x4 acc = {0.f, 0.f, 0.f, 0.f};
  const int nst = K >> 6;
  {
    const u16* ga = A + (size_t)(brow + row) * lda + csrc * 8;
    __builtin_amdgcn_global_load_lds(AS1C(ga), AS3(As + t * 8), 16, 0, 0);
    const u16* gb = BT + (size_t)(bcol + row) * ldbt + csrc * 8;
    __builtin_amdgcn_global_load_lds(AS1C(gb), AS3(Bs + t * 8), 16, 0, 0);
  }
  const int Ra = wr * 16 + r16;                  // A-fragment row
  const int Rb = wc * 16 + r16;                  // B-fragment row
  int cur = 0;
  for (int s = 0; s < nst; ++s) {
    __syncthreads();
    if (s + 1 < nst) {
      int k0 = (s + 1) << 6, nb = cur ^ 1;
      const u16* ga = A + (size_t)(brow + row) * lda + k0 + csrc * 8;
      __builtin_amdgcn_global_load_lds(AS1C(ga), AS3(As + nb * 2048 + t * 8), 16, 0, 0);
      const u16* gb = BT + (size_t)(bcol + row) * ldbt + k0 + csrc * 8;
      __builtin_amdgcn_global_load_lds(AS1C(gb), AS3(Bs + nb * 2048 + t * 8), 16, 0, 0);
    }
    const u16* Asc = As + cur * 2048;
    const u16* Bsc = Bs + cur * 2048;
    #pragma unroll
    for (int kk = 0; kk < 2; ++kk) {
      #pragma unroll
      for (int kgl = 0; kgl < 1; ++kgl) { }      // (placeholder keeps unroll structure minimal)
      int g = kk * 4 + kg;
      bf16x8 af = *(const bf16x8*)&Asc[Ra * 64 + (g ^ (Ra & 7)) * 8];
      bf16x8 bf_ = *(const bf16x8*)&Bsc[Rb * 64 + (g ^ (Rb & 7)) * 8];
      acc = __builtin_amdgcn_mfma_f32_16x16x32_bf16(af, bf_, acc, 0, 0, 0);
    }
    cur ^= 1;
  }
  return acc;
}

// ---------------- the uber kernel: all phases, 8 grid barriers ----------------
__global__ __launch_bounds__(256, 4) void uber(
    const float* __restrict__ ne, const float* __restrict__ ce, const float* __restrict__ adj,
    const float* __restrict__ W1, const float* __restrict__ b1,
    const float* __restrict__ W2, const float* __restrict__ b2,
    const int* __restrict__ pu, const int* __restrict__ pv, const int* __restrict__ nv,
    const int* __restrict__ ps, const int* __restrict__ pd,
    const int* __restrict__ ns, const int* __restrict__ nd,
    float* __restrict__ out, char* __restrict__ ws, int* __restrict__ bar)
{
  __shared__ char sm[21760] __attribute__((aligned(16)));
  u16*   As   = (u16*)sm;                 // 8192
  u16*   Bs   = (u16*)(sm + 8192);        // 8192
  float* gt   = (float*)(sm + 16384);     // 32x33 f32 = 4224
  float* red  = (float*)(sm + 20608);     // 256 f32  = 1024
  float (*tile)[65] = (float(*)[65])sm;   // prep: 64x65 f32 = 16640
  float* redf = (float*)(sm + 16640);     // prep: 1024
  float4* red4 = (float4*)(sm + 17664);   // prep: 8x32 float4 = 4096

  u16*   Ap    = (u16*)(ws + OFF_AP);
  u16*   ATp   = (u16*)(ws + OFF_ATP);
  u16*   Sp    = (u16*)(ws + OFF_SP);
  u16*   T1    = (u16*)(ws + OFF_T1);
  float* G     = (float*)(ws + OFF_G);
  float* Gt    = (float*)(ws + OFF_GT);
  u16*   Gns   = (u16*)(ws + OFF_GNS);
  u16*   Gndt  = (u16*)(ws + OFF_GNDT);
  u16*   W1At  = (u16*)(ws + OFF_W1AT);
  u16*   W1Bt  = (u16*)(ws + OFF_W1BT);
  u16*   w2t   = (u16*)(ws + OFF_W2T);
  u16*   hid   = (u16*)(ws + OFF_HID);
  u16*   nep   = (u16*)(ws + OFF_NEP);
  u16*   cep   = (u16*)(ws + OFF_CEP);
  u16*   hsrcp = (u16*)(ws + OFF_HSRC);
  u16*   hdstp = (u16*)(ws + OFF_HDST);
  float* T2    = (float*)(ws + OFF_T2);
  float* degs  = (float*)(ws + OFF_DEGS);
  float* degd  = (float*)(ws + OFF_DEGD);
  float* part  = (float*)(ws + OFF_PART);

  const int t = threadIdx.x;
  const int w = t >> 6, lane = t & 63;
  const int wr = w >> 1, wc = w & 1;
  const int r16 = lane & 15, kg = lane >> 4;
  const int tx = t & 63, ty = t >> 6;

  // ============ Phase A: packs + degrees (688 jobs) ============
  for (int b = blockIdx.x; b < 688; b += gridDim.x) {
    __syncthreads();
    if (b < 256) {
      int tr = b >> 4, tc = b & 15;
      int l16 = t & 15, rq = t >> 4;
      #pragma unroll
      for (int p = 0; p < 4; p++) {
        int r = p * 16 + rq;
        int gr = tr * 64 + r, gc0 = tc * 64 + l16 * 4;
        float4 v = {0.f, 0.f, 0.f, 0.f};
        if (gr < 1000 && gc0 < 1000) v = *(const float4*)&adj[(size_t)gr * 2000 + 1000 + gc0];
        u16x4 pk = {f2b(v.x), f2b(v.y), f2b(v.z), f2b(v.w)};
        *(u16x4*)&Ap[(size_t)gr * 1024 + gc0] = pk;
        tile[r][l16 * 4 + 0] = v.x;
        tile[r][l16 * 4 + 1] = v.y;
        tile[r][l16 * 4 + 2] = v.z;
        tile[r][l16 * 4 + 3] = v.w;
      }
      __syncthreads();
      #pragma unroll
      for (int p = 0; p < 16; p++) {
        int r = p * 4 + ty;
        ATp[(size_t)(tc * 64 + r) * 1024 + tr * 64 + tx] = f2b(tile[tx][r]);
      }
    } else if (b < 384) {
      int b2 = b - 256;
      int half = b2 >> 6, rem = b2 & 63;
      int jt = rem >> 2, ht = rem & 3;
      #pragma unroll
      for (int p = 0; p < 16; p++) {
        int r = p * 4 + ty;
        int j = jt * 64 + r;
        tile[r][tx] = (j < 1000) ? W1[(size_t)(half * 1000 + j) * 256 + ht * 64 + tx] : 0.f;
      }
      __syncthreads();
      u16* outp = half ? W1Bt : W1At;
      #pragma unroll
      for (int p = 0; p < 16; p++) {
        int r = p * 4 + ty;
        outp[(size_t)(ht * 64 + r) * 1024 + jt * 64 + tx] = f2b(tile[tx][r]);
      }
    } else if (b < 392) {
      int b3 = b - 384;
      int dt = b3 >> 2, kt = b3 & 3;
      #pragma unroll
      for (int p = 0; p < 16; p++) {
        int r = p * 4 + ty;
        tile[r][tx] = W2[(size_t)(kt * 64 + r) * 128 + dt * 64 + tx];
      }
      __syncthreads();
      #pragma unroll
      for (int p = 0; p < 16; p++) {
        int r = p * 4 + ty;
        w2t[(size_t)(dt * 64 + r) * 256 + kt * 64 + tx] = f2b(tile[tx][r]);
      }
    } else if (b < 648) {
      int idx = (b - 392) * 256 + t;
      int i = idx >> 5, d4 = (idx & 31) * 4;
      float4 nv4 = {0.f, 0.f, 0.f, 0.f}, cv4 = {0.f, 0.f, 0.f, 0.f};
      if (i < 2000) {
        nv4 = *(const float4*)&ne[(size_t)i * 128 + d4];
        cv4 = *(const float4*)&ce[(size_t)i * 128 + d4];
      }
      u16x4 nb = {f2b(nv4.x), f2b(nv4.y), f2b(nv4.z), f2b(nv4.w)};
      u16x4 cb = {f2b(cv4.x), f2b(cv4.y), f2b(cv4.z), f2b(cv4.w)};
      u16x4 zz = {0, 0, 0, 0};
      *(u16x4*)&nep[(size_t)i * 128 + d4] = nb;
      *(u16x4*)&cep[(size_t)i * 128 + d4] = cb;
      if (i < 1000)                   *(u16x4*)&hsrcp[(size_t)i * 256 + d4] = nb;
      else if (i < 1024)              *(u16x4*)&hsrcp[(size_t)i * 256 + d4] = zz;
      if (i >= 1000 && i < 2000)      *(u16x4*)&hdstp[(size_t)(i - 1000) * 256 + d4] = nb;
      else if (i >= 2000 && i < 2024) *(u16x4*)&hdstp[(size_t)(i - 1000) * 256 + d4] = zz;
    } else if (b < 656) {
      int jb = b - 648;
      int cx = t & 31, ry = t >> 5;
      int j4 = jb * 128 + cx * 4;
      float4 s = {0.f, 0.f, 0.f, 0.f};
      if (j4 < 1000)
        for (int i = ry; i < 1000; i += 8) {
          float4 v = *(const float4*)&adj[(size_t)i * 2000 + 1000 + j4];
          s.x += v.x; s.y += v.y; s.z += v.z; s.w += v.w;
        }
      red4[ry * 32 + cx] = s;
      __syncthreads();
      if (ry == 0) {
        float4 tot = {0.f, 0.f, 0.f, 0.f};
        #pragma unroll
        for (int k = 0; k < 8; k++) {
          float4 v = red4[k * 32 + cx];
          tot.x += v.x; tot.y += v.y; tot.z += v.z; tot.w += v.w;
        }
        *(float4*)&degd[j4] = tot;
      }
    } else {
      int ib = b - 656;
      int r = t >> 3, c8 = t & 7;
      int i = ib * 32 + r;
      float s = 0.f;
      if (i < 1000)
        for (int k4 = c8 * 4; k4 < 1000; k4 += 32) {
          float4 v = *(const float4*)&adj[(size_t)i * 2000 + 1000 + k4];
          s += v.x + v.y + v.z + v.w;
        }
      redf[t] = s;
      __syncthreads();
      if (c8 == 0) {
        float tot = 0.f;
        #pragma unroll
        for (int k = 0; k < 8; k++) tot += redf[r * 8 + k];
        degs[i] = (i < 1000) ? tot : 0.f;
      }
    }
  }
  gbar(bar, 1);

  // ============ Phase B: T1 = ne@ce^T (4096) + symmetric S = A A^T (528) ============
  for (int b = blockIdx.x; b < 4624; b += gridDim.x) {
    __syncthreads();
    if (b < 4096) {
      int brow = (b >> 6) * 32, bcol = (b & 63) * 32;
      f32x4 acc = gemm_core32(nep, cep, 128, 128, 128, brow, bcol, As, Bs);
      #pragma unroll
      for (int j = 0; j < 4; j++) {
        int row = brow + wr * 16 + kg * 4 + j, col = bcol + wc * 16 + r16;
        T1[(size_t)row * 2048 + col] = f2b(acc[j]);
      }
    } else {
      int s = b - 4096;
      int bi = (int)((sqrtf(8.f * s + 1.f) - 1.f) * 0.5f);
      while (bi * (bi + 1) / 2 > s) bi--;
      while ((bi + 1) * (bi + 2) / 2 <= s) bi++;
      int bj = s - bi * (bi + 1) / 2;
      int brow = bi * 32, bcol = bj * 32;
      f32x4 acc = gemm_core32(Ap, Ap, 1024, 1024, 1024, brow, bcol, As, Bs);
      u16* mir = (u16*)gt;   // 32x33 u16 fits in gt region
      #pragma unroll
      for (int j = 0; j < 4; j++) {
        int lr = wr * 16 + kg * 4 + j, lc = wc * 16 + r16;
        u16 v = f2b(acc[j]);
        Sp[(size_t)(brow + lr) * 1024 + bcol + lc] = v;
        mir[lr * 33 + lc] = v;
      }
      __syncthreads();
      #pragma unroll
      for (int p = 0; p < 4; p++) {
        int idx = p * 256 + t, rr = idx >> 5, cc2 = idx & 31;
        Sp[(size_t)(bcol + rr) * 1024 + brow + cc2] = mir[cc2 * 33 + rr];
      }
    }
  }
  gbar(bar, 2);

  // ============ Phase C1: skipgram gather (391 jobs) — T1 pristine ============
  for (int b = blockIdx.x; b < 391; b += gridDim.x) {
    __syncthreads();
    int s = b * 256 + t;
    float loss = 0.f;
    if (s < BATCH) {
      const u16* trow = T1 + (size_t)pu[s] * 2048;
      const int* nvb = nv + (size_t)s * 5;
      float ap = b2f(trow[pv[s]]);
      ap = fminf(fmaxf(ap, -10.f), 10.f); loss = log1pf(expf(-ap));
      #pragma unroll
      for (int k = 0; k < 5; k++) {
        float a = b2f(trow[nvb[k]]);
        a = fminf(fmaxf(a, -10.f), 10.f);
        loss += log1pf(expf(a));
      }
    }
    red[t] = loss;
    __syncthreads();
    for (int off = 128; off > 0; off >>= 1) {
      if (t < off) red[t] += red[t + off];
      __syncthreads();
    }
    if (t == 0) part[b] = red[0];
  }
  gbar(bar, 3);

  // ============ Phase C2: G gemm (1024 jobs) — overwrites dead T1 space ============
  for (int b = blockIdx.x; b < 1024; b += gridDim.x) {
    __syncthreads();
    int brow = (b >> 5) * 32, bcol = (b & 31) * 32;
    f32x4 acc = gemm_core32(Sp, ATp, 1024, 1024, 1024, brow, bcol, As, Bs);
    #pragma unroll
    for (int j = 0; j < 4; j++) {
      int lr = wr * 16 + kg * 4 + j, lc = wc * 16 + r16;
      int row = brow + lr, col = bcol + lc;
      float a = b2f(Ap[(size_t)row * 1024 + col]);
      float p2 = degs[row] * degd[col];
      float g = (p2 > 0.f) ? (acc[j] * a) / p2 : 0.f;
      G[(size_t)row * 1024 + col] = g;
      gt[lr * 33 + lc] = g;
    }
    __syncthreads();
    #pragma unroll
    for (int p = 0; p < 4; p++) {
      int idx = p * 256 + t, rr = idx >> 5, cc2 = idx & 31;
      Gt[(size_t)(bcol + rr) * 1024 + brow + cc2] = gt[cc2 * 33 + rr];
    }
  }
  gbar(bar, 4);

  // ============ Phase D: row norms (2048) ============
  for (int b = blockIdx.x; b < 2048; b += gridDim.x) {
    __syncthreads();
    const float* src = (b < 1024) ? (G + (size_t)b * 1024) : (Gt + (size_t)(b - 1024) * 1024);
    u16* dst = (b < 1024) ? (Gns + (size_t)b * 1024) : (Gndt + (size_t)(b - 1024) * 1024);
    float v[4];
    float s = 0.f;
    #pragma unroll
    for (int c = 0; c < 4; c++) { v[c] = src[t + 256 * c]; s += v[c] * v[c]; }
    red[t] = s;
    __syncthreads();
    for (int off = 128; off > 0; off >>= 1) {
      if (t < off) red[t] += red[t + off];
      __syncthreads();
    }
    float inv = 1.0f / fmaxf(sqrtf(red[0]), 1e-12f);
    #pragma unroll
    for (int c = 0; c < 4; c++) dst[t + 256 * c] = f2b(v[c] * inv);
  }
  gbar(bar, 5);

  // ============ Phase E: hid = tanh(gamma_hat @ W1 + b1) (512 jobs) ============
  for (int b = blockIdx.x; b < 512; b += gridDim.x) {
    __syncthreads();
    int z = b >> 8, rem = b & 255;
    int brow = (rem & 31) * 32, bcol = (rem >> 5) * 32;
    const u16* Au = z ? Gndt : Gns;
    const u16* Bu = z ? W1At : W1Bt;
    f32x4 acc = gemm_core32(Au, Bu, 1024, 1024, 1024, brow, bcol, As, Bs);
    #pragma unroll
    for (int j = 0; j < 4; j++) {
      int row = brow + wr * 16 + kg * 4 + j;
      int col = bcol + wc * 16 + r16;
      hid[(size_t)(z * 1024 + row) * 256 + col] = f2b(tanhf(acc[j] + b1[col]));
    }
  }
  gbar(bar, 6);

  // ============ Phase F: h[:,128:] = hid @ W2 + b2 (256 jobs) ============
  for (int b = blockIdx.x; b < 256; b += gridDim.x) {
    __syncthreads();
    int brow = (b & 63) * 32, bcol = (b >> 6) * 32;
    f32x4 acc = gemm_core32(hid, w2t, 256, 256, 256, brow, bcol, As, Bs);
    #pragma unroll
    for (int j = 0; j < 4; j++) {
      int row = brow + wr * 16 + kg * 4 + j;
      int col = bcol + wc * 16 + r16;
      u16 hv = f2b(acc[j] + b2[col]);
      if (row < 1024) hsrcp[(size_t)row * 256 + 128 + col] = hv;
      else            hdstp[(size_t)(row - 1024) * 256 + 128 + col] = hv;
    }
  }
  gbar(bar, 7);

  // ============ Phase G: T2 = h_src @ h_dst^T (1024 jobs) ============
  for (int b = blockIdx.x; b < 1024; b += gridDim.x) {
    __syncthreads();
    int brow = (b >> 5) * 32, bcol = (b & 31) * 32;
    f32x4 acc = gemm_core32(hsrcp, hdstp, 256, 256, 256, brow, bcol, As, Bs);
    #pragma unroll
    for (int j = 0; j < 4; j++) {
      int row = brow + wr * 16 + kg * 4 + j;
      int col = bcol + wc * 16 + r16;
      T2[(size_t)row * 1024 + col] = acc[j];
    }
  }
  gbar(bar, 8);

  // ============ Phase H: edge gathers (1563) + loss reduce (1) ============
  for (int b = blockIdx.x; b < 1564; b += gridDim.x) {
    __syncthreads();
    if (b == 1563) {
      float s = 0.f;
      for (int i = t; i < 391; i += 256) s += part[i];
      red[t] = s;
      __syncthreads();
      for (int off = 128; off > 0; off >>= 1) {
        if (t < off) red[t] += red[t + off];
        __syncthreads();
      }
      if (t == 0) out[0] = red[0] / (float)BATCH;
    } else {
      int e = b * 256 + t;
      if (e < 2 * EPE) {
        int src, dst;
        if (e < EPE) { src = ps[e]; dst = pd[e]; }
        else         { src = ns[e - EPE]; dst = nd[e - EPE]; }
        out[1 + e] = T2[(size_t)src * 1024 + dst];
      }
    }
  }
}

// ---------------- launch ----------------
extern "C" void kernel_launch(void* const* d_in, const int* in_sizes, int n_in,
                              void* d_out, int out_size, void* d_ws, size_t ws_size,
                              hipStream_t stream) {
  const float* node_embed    = (const float*)d_in[0];
  const float* context_embed = (const float*)d_in[1];
  const float* adj           = (const float*)d_in[2];
  const float* W1            = (const float*)d_in[3];
  const float* b1            = (const float*)d_in[4];
  const float* W2            = (const float*)d_in[5];
  const float* b2            = (const float*)d_in[6];
  const int* pos_u   = (const int*)d_in[7];
  const int* pos_v   = (const int*)d_in[8];
  const int* neg_v   = (const int*)d_in[9];
  const int* pos_src = (const int*)d_in[10];
  const int* pos_dst = (const int*)d_in[11];
  const int* neg_src = (const int*)d_in[12];
  const int* neg_dst = (const int*)d_in[13];
  float* out = (float*)d_out;
  char* ws = (char*)d_ws;
  int* bar = (int*)(ws + OFF_BAR);

  // zero the barrier counter (the only extra graph node)
  hipMemsetAsync(bar, 0, 64, stream);

  uber<<<NBLK, 256, 0, stream>>>(node_embed, context_embed, adj, W1, b1, W2, b2,
      pos_u, pos_v, neg_v, pos_src, pos_dst, neg_src, neg_dst, out, ws, bar);
}

// Round 10
// 117.679 us; speedup vs baseline: 7.8172x; 7.8172x over previous
//
#include <hip/hip_runtime.h>
#include <hip/hip_bf16.h>

typedef __attribute__((ext_vector_type(8))) short bf16x8;
typedef __attribute__((ext_vector_type(4))) float f32x4;
typedef __attribute__((ext_vector_type(4))) unsigned short u16x4;
typedef unsigned short u16;

#define BATCH 100000
#define EPE 200000

// ---- workspace layout (bytes), ~35.7 MB of the 256 MB ws; NO aliasing ----
#define OFF_AP    ((size_t)0)          // u16 [1024*1024]
#define OFF_ATP   ((size_t)2097152)    // u16 [1024*1024]
#define OFF_SP    ((size_t)4194304)    // u16 [1024*1024]
#define OFF_T1    ((size_t)6291456)    // u16 [2048*2048]
#define OFF_G     ((size_t)14680064)   // f32 [1024*1024]
#define OFF_GT    ((size_t)18874368)   // f32 [1024*1024]
#define OFF_GNS   ((size_t)23068672)   // u16 [1024*1024]
#define OFF_GNDT  ((size_t)25165824)   // u16 [1024*1024]
#define OFF_W1AT  ((size_t)27262976)   // u16 [256*1024]
#define OFF_W1BT  ((size_t)27787264)   // u16 [256*1024]
#define OFF_W2T   ((size_t)28311552)   // u16 [128*256]
#define OFF_HID   ((size_t)28377088)   // u16 [2048*256]
#define OFF_NEP   ((size_t)29425664)   // u16 [2048*128]
#define OFF_CEP   ((size_t)29950208)   // u16 [2048*128]
#define OFF_HSRC  ((size_t)30474752)   // u16 [1024*256]
#define OFF_HDST  ((size_t)30999296)   // u16 [1024*256]
#define OFF_T2    ((size_t)31523840)   // f32 [1024*1024]
#define OFF_DEGS  ((size_t)35718144)   // f32 [1024]
#define OFF_DEGD  ((size_t)35722240)   // f32 [1024]
#define OFF_PART  ((size_t)35726336)   // f32 [391]

__device__ __forceinline__ u16 f2b(float f) {
  union { float f; unsigned u; } v; v.f = f;
  unsigned r = v.u + 0x7fffu + ((v.u >> 16) & 1u);
  return (u16)(r >> 16);
}
__device__ __forceinline__ float b2f(u16 h) {
  union { unsigned u; float f; } v; v.u = ((unsigned)h) << 16;
  return v.f;
}

#define AS1C(p) ((const __attribute__((address_space(1))) void*)(p))
#define AS3(p)  ((__attribute__((address_space(3))) void*)(p))

// ---------------- fused prep: all packs + degrees, vectorized (proven R6) ----------------
__global__ __launch_bounds__(256) void prep(const float* __restrict__ adj,
    const float* __restrict__ W1, const float* __restrict__ W2,
    const float* __restrict__ ne, const float* __restrict__ ce,
    u16* __restrict__ Ap, u16* __restrict__ ATp,
    u16* __restrict__ W1At, u16* __restrict__ W1Bt, u16* __restrict__ w2t,
    u16* __restrict__ nep, u16* __restrict__ cep,
    u16* __restrict__ hsrcp, u16* __restrict__ hdstp,
    float* __restrict__ degd, float* __restrict__ degs) {
  __shared__ float tile[64][65];
  __shared__ float redf[256];
  __shared__ float4 red4[8][32];
  int b = blockIdx.x;
  int t = threadIdx.x;
  int tx = t & 63, ty = t >> 6;
  if (b < 256) {
    int tr = b >> 4, tc = b & 15;
    int l16 = t & 15, rq = t >> 4;
    #pragma unroll
    for (int p = 0; p < 4; p++) {
      int r = p * 16 + rq;
      int gr = tr * 64 + r, gc0 = tc * 64 + l16 * 4;
      float4 v = {0.f, 0.f, 0.f, 0.f};
      if (gr < 1000 && gc0 < 1000) v = *(const float4*)&adj[(size_t)gr * 2000 + 1000 + gc0];
      u16x4 pk = {f2b(v.x), f2b(v.y), f2b(v.z), f2b(v.w)};
      *(u16x4*)&Ap[(size_t)gr * 1024 + gc0] = pk;
      tile[r][l16 * 4 + 0] = v.x;
      tile[r][l16 * 4 + 1] = v.y;
      tile[r][l16 * 4 + 2] = v.z;
      tile[r][l16 * 4 + 3] = v.w;
    }
    __syncthreads();
    #pragma unroll
    for (int p = 0; p < 16; p++) {
      int r = p * 4 + ty;
      ATp[(size_t)(tc * 64 + r) * 1024 + tr * 64 + tx] = f2b(tile[tx][r]);
    }
  } else if (b < 384) {
    int b2 = b - 256;
    int half = b2 >> 6, rem = b2 & 63;
    int jt = rem >> 2, ht = rem & 3;
    #pragma unroll
    for (int p = 0; p < 16; p++) {
      int r = p * 4 + ty;
      int j = jt * 64 + r;
      tile[r][tx] = (j < 1000) ? W1[(size_t)(half * 1000 + j) * 256 + ht * 64 + tx] : 0.f;
    }
    __syncthreads();
    u16* outp = half ? W1Bt : W1At;
    #pragma unroll
    for (int p = 0; p < 16; p++) {
      int r = p * 4 + ty;
      outp[(size_t)(ht * 64 + r) * 1024 + jt * 64 + tx] = f2b(tile[tx][r]);
    }
  } else if (b < 392) {
    int b3 = b - 384;
    int dt = b3 >> 2, kt = b3 & 3;
    #pragma unroll
    for (int p = 0; p < 16; p++) {
      int r = p * 4 + ty;
      tile[r][tx] = W2[(size_t)(kt * 64 + r) * 128 + dt * 64 + tx];
    }
    __syncthreads();
    #pragma unroll
    for (int p = 0; p < 16; p++) {
      int r = p * 4 + ty;
      w2t[(size_t)(dt * 64 + r) * 256 + kt * 64 + tx] = f2b(tile[tx][r]);
    }
  } else if (b < 648) {
    int idx = (b - 392) * 256 + t;
    int i = idx >> 5, d4 = (idx & 31) * 4;
    float4 nv4 = {0.f, 0.f, 0.f, 0.f}, cv4 = {0.f, 0.f, 0.f, 0.f};
    if (i < 2000) {
      nv4 = *(const float4*)&ne[(size_t)i * 128 + d4];
      cv4 = *(const float4*)&ce[(size_t)i * 128 + d4];
    }
    u16x4 nb = {f2b(nv4.x), f2b(nv4.y), f2b(nv4.z), f2b(nv4.w)};
    u16x4 cb = {f2b(cv4.x), f2b(cv4.y), f2b(cv4.z), f2b(cv4.w)};
    u16x4 zz = {0, 0, 0, 0};
    *(u16x4*)&nep[(size_t)i * 128 + d4] = nb;
    *(u16x4*)&cep[(size_t)i * 128 + d4] = cb;
    if (i < 1000)                   *(u16x4*)&hsrcp[(size_t)i * 256 + d4] = nb;
    else if (i < 1024)              *(u16x4*)&hsrcp[(size_t)i * 256 + d4] = zz;
    if (i >= 1000 && i < 2000)      *(u16x4*)&hdstp[(size_t)(i - 1000) * 256 + d4] = nb;
    else if (i >= 2000 && i < 2024) *(u16x4*)&hdstp[(size_t)(i - 1000) * 256 + d4] = zz;
  } else if (b < 656) {
    int jb = b - 648;
    int cx = t & 31, ry = t >> 5;
    int j4 = jb * 128 + cx * 4;
    float4 s = {0.f, 0.f, 0.f, 0.f};
    if (j4 < 1000)
      for (int i = ry; i < 1000; i += 8) {
        float4 v = *(const float4*)&adj[(size_t)i * 2000 + 1000 + j4];
        s.x += v.x; s.y += v.y; s.z += v.z; s.w += v.w;
      }
    red4[ry][cx] = s;
    __syncthreads();
    if (ry == 0) {
      float4 tot = {0.f, 0.f, 0.f, 0.f};
      #pragma unroll
      for (int k = 0; k < 8; k++) {
        float4 v = red4[k][cx];
        tot.x += v.x; tot.y += v.y; tot.z += v.z; tot.w += v.w;
      }
      *(float4*)&degd[j4] = tot;
    }
  } else {
    int ib = b - 656;
    int r = t >> 3, c8 = t & 7;
    int i = ib * 32 + r;
    float s = 0.f;
    if (i < 1000)
      for (int k4 = c8 * 4; k4 < 1000; k4 += 32) {
        float4 v = *(const float4*)&adj[(size_t)i * 2000 + 1000 + k4];
        s += v.x + v.y + v.z + v.w;
      }
    redf[t] = s;
    __syncthreads();
    if (c8 == 0) {
      float tot = 0.f;
      #pragma unroll
      for (int k = 0; k < 8; k++) tot += redf[r * 8 + k];
      degs[i] = (i < 1000) ? tot : 0.f;
    }
  }
}

// ---------------- 64x64-tile bf16 MFMA core, 2-phase dbuf, XOR-swizzled LDS ----------------
struct Acc22 { f32x4 a[2][2]; };
__device__ __forceinline__ Acc22 gemm_core64(const u16* A, const u16* BT,
    int K, int lda, int ldbt, int brow, int bcol, u16* As, u16* Bs) {
  const int t = threadIdx.x;
  const int w = t >> 6, lane = t & 63;
  const int wr = w >> 1, wc = w & 1;
  const int r16 = lane & 15, kg = lane >> 4;
  Acc22 acc;
  #pragma unroll
  for (int m = 0; m < 2; m++)
    #pragma unroll
    for (int n = 0; n < 2; n++) {
      f32x4 z = {0.f, 0.f, 0.f, 0.f};
      acc.a[m][n] = z;
    }
  auto stage = [&](u16* dA, u16* dB, int k0) {
    #pragma unroll
    for (int it = 0; it < 2; ++it) {
      int chunk = it * 256 + t;
      int row = chunk >> 3, c = (chunk & 7) ^ (row & 7);   // pre-swizzled source chunk
      const u16* ga = A + (size_t)(brow + row) * lda + k0 + c * 8;
      __builtin_amdgcn_global_load_lds(AS1C(ga), AS3(dA + chunk * 8), 16, 0, 0);
      const u16* gb = BT + (size_t)(bcol + row) * ldbt + k0 + c * 8;
      __builtin_amdgcn_global_load_lds(AS1C(gb), AS3(dB + chunk * 8), 16, 0, 0);
    }
  };
  const int nst = K >> 6;
  stage(As, Bs, 0);
  int cur = 0;
  for (int s = 0; s < nst; ++s) {
    __syncthreads();
    if (s + 1 < nst) stage(As + (cur ^ 1) * 4096, Bs + (cur ^ 1) * 4096, (s + 1) << 6);
    const u16* Asc = As + cur * 4096;
    const u16* Bsc = Bs + cur * 4096;
    #pragma unroll
    for (int kk = 0; kk < 2; ++kk) {
      int g = kk * 4 + kg;
      bf16x8 af[2], bfr[2];
      #pragma unroll
      for (int m = 0; m < 2; m++) {
        int Ra = wr * 32 + m * 16 + r16;
        af[m] = *(const bf16x8*)&Asc[Ra * 64 + ((g ^ (Ra & 7)) * 8)];
      }
      #pragma unroll
      for (int n = 0; n < 2; n++) {
        int Rb = wc * 32 + n * 16 + r16;
        bfr[n] = *(const bf16x8*)&Bsc[Rb * 64 + ((g ^ (Rb & 7)) * 8)];
      }
      #pragma unroll
      for (int m = 0; m < 2; m++)
        #pragma unroll
        for (int n = 0; n < 2; n++)
          acc.a[m][n] = __builtin_amdgcn_mfma_f32_16x16x32_bf16(af[m], bfr[n], acc.a[m][n], 0, 0, 0);
    }
    cur ^= 1;
  }
  return acc;
}

// ---------------- mega1: T1 = ne@ce^T (1024 jobs) + symmetric S = A A^T (136 jobs) ----------------
__global__ __launch_bounds__(256) void mega1(const u16* __restrict__ nep, const u16* __restrict__ cep,
    const u16* __restrict__ Ap, u16* __restrict__ T1, u16* __restrict__ Sp) {
  __shared__ u16 As[2 * 4096];
  __shared__ u16 Bs[2 * 4096];
  __shared__ u16 mir[64 * 65];
  int b = blockIdx.x;
  const int t = threadIdx.x;
  const int w = t >> 6, lane = t & 63;
  const int wr = w >> 1, wc = w & 1;
  const int r16 = lane & 15, kg = lane >> 4;
  if (b < 1024) {
    int brow = (b >> 5) * 64, bcol = (b & 31) * 64;
    Acc22 acc = gemm_core64(nep, cep, 128, 128, 128, brow, bcol, As, Bs);
    #pragma unroll
    for (int m = 0; m < 2; m++)
      #pragma unroll
      for (int n = 0; n < 2; n++)
        #pragma unroll
        for (int j = 0; j < 4; j++) {
          int row = brow + wr * 32 + m * 16 + kg * 4 + j;
          int col = bcol + wc * 32 + n * 16 + r16;
          T1[(size_t)row * 2048 + col] = f2b(acc.a[m][n][j]);
        }
  } else {
    int s = b - 1024;                       // lower-tri tile index over 16x16, 136 total
    int bi = (int)((sqrtf(8.f * s + 1.f) - 1.f) * 0.5f);
    while (bi * (bi + 1) / 2 > s) bi--;
    while ((bi + 1) * (bi + 2) / 2 <= s) bi++;
    int bj = s - bi * (bi + 1) / 2;
    int brow = bi * 64, bcol = bj * 64;
    Acc22 acc = gemm_core64(Ap, Ap, 1024, 1024, 1024, brow, bcol, As, Bs);
    #pragma unroll
    for (int m = 0; m < 2; m++)
      #pragma unroll
      for (int n = 0; n < 2; n++)
        #pragma unroll
        for (int j = 0; j < 4; j++) {
          int lr = wr * 32 + m * 16 + kg * 4 + j;
          int lc = wc * 32 + n * 16 + r16;
          u16 v = f2b(acc.a[m][n][j]);
          Sp[(size_t)(brow + lr) * 1024 + bcol + lc] = v;
          mir[lr * 65 + lc] = v;
        }
    __syncthreads();
    #pragma unroll
    for (int p = 0; p < 16; p++) {
      int idx = p * 256 + t, rr = idx >> 6, cc = idx & 63;
      Sp[(size_t)(bcol + rr) * 1024 + brow + cc] = mir[cc * 65 + rr];
    }
  }
}

// ---------------- mega2: G gemm (256 jobs, disjoint buffers) + skipgram gather (391) ----------------
__global__ __launch_bounds__(256) void mega2(const u16* __restrict__ Sp, const u16* __restrict__ ATp,
    const u16* __restrict__ Ap, const float* __restrict__ degs, const float* __restrict__ degd,
    float* __restrict__ G, float* __restrict__ Gt,
    const u16* __restrict__ T1, const int* __restrict__ pu, const int* __restrict__ pv,
    const int* __restrict__ nv, float* __restrict__ partial) {
  __shared__ char sm[49664] __attribute__((aligned(16)));
  u16* As = (u16*)sm;                      // 16384 B
  u16* Bs = (u16*)(sm + 16384);            // 16384 B
  float* gtile = (float*)(sm + 32768);     // 64*65 f32 = 16640 B (gemm path)
  float* red = (float*)sm;                 // 1024 B (gather path)
  int b = blockIdx.x;
  const int t = threadIdx.x;
  if (b >= 256) {
    int s = (b - 256) * 256 + t;
    float loss = 0.f;
    if (s < BATCH) {
      const u16* trow = T1 + (size_t)pu[s] * 2048;
      const int* nvb = nv + (size_t)s * 5;
      float ap = b2f(trow[pv[s]]);
      ap = fminf(fmaxf(ap, -10.f), 10.f); loss = log1pf(expf(-ap));
      #pragma unroll
      for (int k = 0; k < 5; k++) {
        float a = b2f(trow[nvb[k]]);
        a = fminf(fmaxf(a, -10.f), 10.f);
        loss += log1pf(expf(a));
      }
    }
    red[t] = loss;
    __syncthreads();
    for (int off = 128; off > 0; off >>= 1) {
      if (t < off) red[t] += red[t + off];
      __syncthreads();
    }
    if (t == 0) partial[b - 256] = red[0];
    return;
  }
  const int w = t >> 6, lane = t & 63;
  const int wr = w >> 1, wc = w & 1;
  const int r16 = lane & 15, kg = lane >> 4;
  int brow = (b >> 4) * 64, bcol = (b & 15) * 64;
  Acc22 acc = gemm_core64(Sp, ATp, 1024, 1024, 1024, brow, bcol, As, Bs);
  #pragma unroll
  for (int m = 0; m < 2; m++)
    #pragma unroll
    for (int n = 0; n < 2; n++)
      #pragma unroll
      for (int j = 0; j < 4; j++) {
        int lr = wr * 32 + m * 16 + kg * 4 + j;
        int lc = wc * 32 + n * 16 + r16;
        int row = brow + lr, col = bcol + lc;
        float a = b2f(Ap[(size_t)row * 1024 + col]);
        float p2 = degs[row] * degd[col];
        float g = (p2 > 0.f) ? (acc.a[m][n][j] * a) / p2 : 0.f;
        G[(size_t)row * 1024 + col] = g;
        gtile[lr * 65 + lc] = g;
      }
  __syncthreads();
  #pragma unroll
  for (int p = 0; p < 16; p++) {
    int idx = p * 256 + t, rr = idx >> 6, cc = idx & 63;
    Gt[(size_t)(bcol + rr) * 1024 + brow + cc] = gtile[cc * 65 + rr];
  }
}

// ---------------- fused norms: rows of G -> Gns; rows of Gt -> Gndt ----------------
__global__ __launch_bounds__(256) void normk(const float* __restrict__ G, const float* __restrict__ Gt,
                                             u16* __restrict__ Gns, u16* __restrict__ Gndt) {
  __shared__ float red[256];
  int b = blockIdx.x;
  const float* src = (b < 1024) ? (G + (size_t)b * 1024) : (Gt + (size_t)(b - 1024) * 1024);
  u16* dst = (b < 1024) ? (Gns + (size_t)b * 1024) : (Gndt + (size_t)(b - 1024) * 1024);
  float v[4];
  float s = 0.f;
  #pragma unroll
  for (int c = 0; c < 4; c++) { v[c] = src[threadIdx.x + 256 * c]; s += v[c] * v[c]; }
  red[threadIdx.x] = s;
  __syncthreads();
  for (int off = 128; off > 0; off >>= 1) {
    if (threadIdx.x < off) red[threadIdx.x] += red[threadIdx.x + off];
    __syncthreads();
  }
  float inv = 1.0f / fmaxf(sqrtf(red[0]), 1e-12f);
  #pragma unroll
  for (int c = 0; c < 4; c++) dst[threadIdx.x + 256 * c] = f2b(v[c] * inv);
}

// ---------------- hid = tanh(gamma_hat @ W1 + b1): 128 jobs (z = b>>6) ----------------
__global__ __launch_bounds__(256) void gemm_hid(const u16* __restrict__ Gns, const u16* __restrict__ W1Bt,
    const u16* __restrict__ Gndt, const u16* __restrict__ W1At,
    const float* __restrict__ b1, u16* __restrict__ hid) {
  __shared__ u16 As[2 * 4096];
  __shared__ u16 Bs[2 * 4096];
  const int t = threadIdx.x;
  const int w = t >> 6, lane = t & 63;
  const int wr = w >> 1, wc = w & 1;
  const int r16 = lane & 15, kg = lane >> 4;
  int b = blockIdx.x;
  int z = b >> 6, rem = b & 63;
  int brow = (rem & 15) * 64, bcol = (rem >> 4) * 64;
  const u16* Au = z ? Gndt : Gns;
  const u16* Bu = z ? W1At : W1Bt;
  Acc22 acc = gemm_core64(Au, Bu, 1024, 1024, 1024, brow, bcol, As, Bs);
  #pragma unroll
  for (int m = 0; m < 2; m++)
    #pragma unroll
    for (int n = 0; n < 2; n++)
      #pragma unroll
      for (int j = 0; j < 4; j++) {
        int row = brow + wr * 32 + m * 16 + kg * 4 + j;
        int col = bcol + wc * 32 + n * 16 + r16;
        hid[(size_t)((z << 10) + row) * 256 + col] = f2b(tanhf(acc.a[m][n][j] + b1[col]));
      }
}

// ---------------- h[:,128:] = hid @ W2 + b2 (64 jobs) ----------------
__global__ __launch_bounds__(256) void gemm_w2(const u16* __restrict__ hid, const u16* __restrict__ w2t,
    const float* __restrict__ b2, u16* __restrict__ hsrcp, u16* __restrict__ hdstp) {
  __shared__ u16 As[2 * 4096];
  __shared__ u16 Bs[2 * 4096];
  const int t = threadIdx.x;
  const int w = t >> 6, lane = t & 63;
  const int wr = w >> 1, wc = w & 1;
  const int r16 = lane & 15, kg = lane >> 4;
  int b = blockIdx.x;
  int brow = (b >> 1) * 64, bcol = (b & 1) * 64;
  Acc22 acc = gemm_core64(hid, w2t, 256, 256, 256, brow, bcol, As, Bs);
  #pragma unroll
  for (int m = 0; m < 2; m++)
    #pragma unroll
    for (int n = 0; n < 2; n++)
      #pragma unroll
      for (int j = 0; j < 4; j++) {
        int row = brow + wr * 32 + m * 16 + kg * 4 + j;
        int col = bcol + wc * 32 + n * 16 + r16;
        u16 hv = f2b(acc.a[m][n][j] + b2[col]);
        if (row < 1024) hsrcp[(size_t)row * 256 + 128 + col] = hv;
        else            hdstp[(size_t)(row - 1024) * 256 + 128 + col] = hv;
      }
}

// ---------------- T2 = h_src @ h_dst^T (256 jobs) ----------------
__global__ __launch_bounds__(256) void gemm_t2(const u16* __restrict__ hsrcp, const u16* __restrict__ hdstp,
    float* __restrict__ T2) {
  __shared__ u16 As[2 * 4096];
  __shared__ u16 Bs[2 * 4096];
  const int t = threadIdx.x;
  const int w = t >> 6, lane = t & 63;
  const int wr = w >> 1, wc = w & 1;
  const int r16 = lane & 15, kg = lane >> 4;
  int b = blockIdx.x;
  int brow = (b >> 4) * 64, bcol = (b & 15) * 64;
  Acc22 acc = gemm_core64(hsrcp, hdstp, 256, 256, 256, brow, bcol, As, Bs);
  #pragma unroll
  for (int m = 0; m < 2; m++)
    #pragma unroll
    for (int n = 0; n < 2; n++)
      #pragma unroll
      for (int j = 0; j < 4; j++) {
        int row = brow + wr * 32 + m * 16 + kg * 4 + j;
        int col = bcol + wc * 32 + n * 16 + r16;
        T2[(size_t)row * 1024 + col] = acc.a[m][n][j];
      }
}

// ---------------- edge gather from T2 + final loss reduce (block 1563) ----------------
__global__ __launch_bounds__(256) void edge_loss(const float* __restrict__ T2,
    const float* __restrict__ partial,
    const int* __restrict__ ps, const int* __restrict__ pd,
    const int* __restrict__ ns, const int* __restrict__ nd,
    float* __restrict__ out) {
  if (blockIdx.x == 1563) {
    __shared__ float red[256];
    float s = 0.f;
    for (int i = threadIdx.x; i < 391; i += 256) s += partial[i];
    red[threadIdx.x] = s;
    __syncthreads();
    for (int off = 128; off > 0; off >>= 1) {
      if (threadIdx.x < off) red[threadIdx.x] += red[threadIdx.x + off];
      __syncthreads();
    }
    if (threadIdx.x == 0) out[0] = red[0] / (float)BATCH;
    return;
  }
  int e = blockIdx.x * 256 + threadIdx.x;
  if (e >= 2 * EPE) return;
  int src, dst;
  if (e < EPE) { src = ps[e]; dst = pd[e]; }
  else         { src = ns[e - EPE]; dst = nd[e - EPE]; }
  out[1 + e] = T2[(size_t)src * 1024 + dst];
}

// ---------------- launch ----------------
extern "C" void kernel_launch(void* const* d_in, const int* in_sizes, int n_in,
                              void* d_out, int out_size, void* d_ws, size_t ws_size,
                              hipStream_t stream) {
  const float* node_embed    = (const float*)d_in[0];
  const float* context_embed = (const float*)d_in[1];
  const float* adj           = (const float*)d_in[2];
  const float* W1            = (const float*)d_in[3];
  const float* b1            = (const float*)d_in[4];
  const float* W2            = (const float*)d_in[5];
  const float* b2            = (const float*)d_in[6];
  const int* pos_u   = (const int*)d_in[7];
  const int* pos_v   = (const int*)d_in[8];
  const int* neg_v   = (const int*)d_in[9];
  const int* pos_src = (const int*)d_in[10];
  const int* pos_dst = (const int*)d_in[11];
  const int* neg_src = (const int*)d_in[12];
  const int* neg_dst = (const int*)d_in[13];
  float* out = (float*)d_out;

  char* ws = (char*)d_ws;
  u16*   Ap    = (u16*)(ws + OFF_AP);
  u16*   ATp   = (u16*)(ws + OFF_ATP);
  u16*   Sp    = (u16*)(ws + OFF_SP);
  u16*   T1    = (u16*)(ws + OFF_T1);
  float* G     = (float*)(ws + OFF_G);
  float* Gt    = (float*)(ws + OFF_GT);
  u16*   Gns   = (u16*)(ws + OFF_GNS);
  u16*   Gndt  = (u16*)(ws + OFF_GNDT);
  u16*   W1At  = (u16*)(ws + OFF_W1AT);
  u16*   W1Bt  = (u16*)(ws + OFF_W1BT);
  u16*   w2t   = (u16*)(ws + OFF_W2T);
  u16*   hid   = (u16*)(ws + OFF_HID);
  u16*   nep   = (u16*)(ws + OFF_NEP);
  u16*   cep   = (u16*)(ws + OFF_CEP);
  u16*   hsrcp = (u16*)(ws + OFF_HSRC);
  u16*   hdstp = (u16*)(ws + OFF_HDST);
  float* T2    = (float*)(ws + OFF_T2);
  float* degs  = (float*)(ws + OFF_DEGS);
  float* degd  = (float*)(ws + OFF_DEGD);
  float* part  = (float*)(ws + OFF_PART);

  // 1. packs + degrees
  prep<<<688, 256, 0, stream>>>(adj, W1, W2, node_embed, context_embed,
                                Ap, ATp, W1At, W1Bt, w2t, nep, cep, hsrcp, hdstp, degd, degs);
  // 2. T1 (1024 jobs, 64^2) + symmetric S (136 jobs, 64^2)
  mega1<<<1160, 256, 0, stream>>>(nep, cep, Ap, T1, Sp);
  // 3. G gemm (256 jobs, 64^2; disjoint G/Gt) + skipgram gather (391) — race-free
  mega2<<<647, 256, 0, stream>>>(Sp, ATp, Ap, degs, degd, G, Gt, T1, pos_u, pos_v, neg_v, part);
  // 4. row norms of G and Gt -> bf16
  normk<<<2048, 256, 0, stream>>>(G, Gt, Gns, Gndt);
  // 5. hid = tanh(gamma_hat @ W1 + b1)
  gemm_hid<<<128, 256, 0, stream>>>(Gns, W1Bt, Gndt, W1At, b1, hid);
  // 6. h[:,128:] = hid @ W2 + b2
  gemm_w2<<<64, 256, 0, stream>>>(hid, w2t, b2, hsrcp, hdstp);
  // 7. T2 = h_src @ h_dst^T
  gemm_t2<<<256, 256, 0, stream>>>(hsrcp, hdstp, T2);
  // 8. edge gathers + final loss reduce
  edge_loss<<<1564, 256, 0, stream>>>(T2, part, pos_src, pos_dst, neg_src, neg_dst, out);
}

// Round 11
// 103.236 us; speedup vs baseline: 8.9109x; 1.1399x over previous
//
#include <hip/hip_runtime.h>
#include <hip/hip_bf16.h>

typedef __attribute__((ext_vector_type(8))) short bf16x8;
typedef __attribute__((ext_vector_type(4))) float f32x4;
typedef __attribute__((ext_vector_type(4))) unsigned short u16x4;
typedef unsigned short u16;

#define BATCH 100000
#define EPE 200000

// ---- workspace layout (bytes), ~27.6 MB, no aliasing ----
#define OFF_AP    ((size_t)0)          // u16 [1024*1024]
#define OFF_ATP   ((size_t)2097152)    // u16 [1024*1024]
#define OFF_SP    ((size_t)4194304)    // u16 [1024*1024]
#define OFF_T1    ((size_t)6291456)    // u16 [2048*2048]
#define OFF_GNS   ((size_t)14680064)   // u16 [1024*1024]  bf16 Gamma (src rows)
#define OFF_GNDT  ((size_t)16777216)   // u16 [1024*1024]  bf16 Gamma^T (dst rows)
#define OFF_W1AT  ((size_t)18874368)   // u16 [256*1024]
#define OFF_W1BT  ((size_t)19398656)   // u16 [256*1024]
#define OFF_W2T   ((size_t)19922944)   // u16 [128*256]
#define OFF_HID   ((size_t)19988480)   // u16 [2048*256]
#define OFF_NEP   ((size_t)21037056)   // u16 [2048*128]
#define OFF_CEP   ((size_t)21561344)   // u16 [2048*128]
#define OFF_HSRC  ((size_t)22085632)   // u16 [1024*256]
#define OFF_HDST  ((size_t)22609920)   // u16 [1024*256]
#define OFF_T2    ((size_t)23134208)   // f32 [1024*1024]
#define OFF_ROWP  ((size_t)27328512)   // f32 [32*1024] per-coltile row sumsq partials
#define OFF_COLP  ((size_t)27459584)   // f32 [32*1024] per-rowtile col sumsq partials
#define OFF_DEGS  ((size_t)27590656)   // f32 [1024]
#define OFF_DEGD  ((size_t)27594752)   // f32 [1024]
#define OFF_PART  ((size_t)27598848)   // f32 [391]

__device__ __forceinline__ u16 f2b(float f) {
  union { float f; unsigned u; } v; v.f = f;
  unsigned r = v.u + 0x7fffu + ((v.u >> 16) & 1u);
  return (u16)(r >> 16);
}
__device__ __forceinline__ float b2f(u16 h) {
  union { unsigned u; float f; } v; v.u = ((unsigned)h) << 16;
  return v.f;
}

#define AS1C(p) ((const __attribute__((address_space(1))) void*)(p))
#define AS3(p)  ((__attribute__((address_space(3))) void*)(p))

// ---------------- fused prep: all packs + degrees, vectorized (proven R6) ----------------
__global__ __launch_bounds__(256) void prep(const float* __restrict__ adj,
    const float* __restrict__ W1, const float* __restrict__ W2,
    const float* __restrict__ ne, const float* __restrict__ ce,
    u16* __restrict__ Ap, u16* __restrict__ ATp,
    u16* __restrict__ W1At, u16* __restrict__ W1Bt, u16* __restrict__ w2t,
    u16* __restrict__ nep, u16* __restrict__ cep,
    u16* __restrict__ hsrcp, u16* __restrict__ hdstp,
    float* __restrict__ degd, float* __restrict__ degs) {
  __shared__ float tile[64][65];
  __shared__ float redf[256];
  __shared__ float4 red4[8][32];
  int b = blockIdx.x;
  int t = threadIdx.x;
  int tx = t & 63, ty = t >> 6;
  if (b < 256) {
    int tr = b >> 4, tc = b & 15;
    int l16 = t & 15, rq = t >> 4;
    #pragma unroll
    for (int p = 0; p < 4; p++) {
      int r = p * 16 + rq;
      int gr = tr * 64 + r, gc0 = tc * 64 + l16 * 4;
      float4 v = {0.f, 0.f, 0.f, 0.f};
      if (gr < 1000 && gc0 < 1000) v = *(const float4*)&adj[(size_t)gr * 2000 + 1000 + gc0];
      u16x4 pk = {f2b(v.x), f2b(v.y), f2b(v.z), f2b(v.w)};
      *(u16x4*)&Ap[(size_t)gr * 1024 + gc0] = pk;
      tile[r][l16 * 4 + 0] = v.x;
      tile[r][l16 * 4 + 1] = v.y;
      tile[r][l16 * 4 + 2] = v.z;
      tile[r][l16 * 4 + 3] = v.w;
    }
    __syncthreads();
    #pragma unroll
    for (int p = 0; p < 16; p++) {
      int r = p * 4 + ty;
      ATp[(size_t)(tc * 64 + r) * 1024 + tr * 64 + tx] = f2b(tile[tx][r]);
    }
  } else if (b < 384) {
    int b2 = b - 256;
    int half = b2 >> 6, rem = b2 & 63;
    int jt = rem >> 2, ht = rem & 3;
    #pragma unroll
    for (int p = 0; p < 16; p++) {
      int r = p * 4 + ty;
      int j = jt * 64 + r;
      tile[r][tx] = (j < 1000) ? W1[(size_t)(half * 1000 + j) * 256 + ht * 64 + tx] : 0.f;
    }
    __syncthreads();
    u16* outp = half ? W1Bt : W1At;
    #pragma unroll
    for (int p = 0; p < 16; p++) {
      int r = p * 4 + ty;
      outp[(size_t)(ht * 64 + r) * 1024 + jt * 64 + tx] = f2b(tile[tx][r]);
    }
  } else if (b < 392) {
    int b3 = b - 384;
    int dt = b3 >> 2, kt = b3 & 3;
    #pragma unroll
    for (int p = 0; p < 16; p++) {
      int r = p * 4 + ty;
      tile[r][tx] = W2[(size_t)(kt * 64 + r) * 128 + dt * 64 + tx];
    }
    __syncthreads();
    #pragma unroll
    for (int p = 0; p < 16; p++) {
      int r = p * 4 + ty;
      w2t[(size_t)(dt * 64 + r) * 256 + kt * 64 + tx] = f2b(tile[tx][r]);
    }
  } else if (b < 648) {
    int idx = (b - 392) * 256 + t;
    int i = idx >> 5, d4 = (idx & 31) * 4;
    float4 nv4 = {0.f, 0.f, 0.f, 0.f}, cv4 = {0.f, 0.f, 0.f, 0.f};
    if (i < 2000) {
      nv4 = *(const float4*)&ne[(size_t)i * 128 + d4];
      cv4 = *(const float4*)&ce[(size_t)i * 128 + d4];
    }
    u16x4 nb = {f2b(nv4.x), f2b(nv4.y), f2b(nv4.z), f2b(nv4.w)};
    u16x4 cb = {f2b(cv4.x), f2b(cv4.y), f2b(cv4.z), f2b(cv4.w)};
    u16x4 zz = {0, 0, 0, 0};
    *(u16x4*)&nep[(size_t)i * 128 + d4] = nb;
    *(u16x4*)&cep[(size_t)i * 128 + d4] = cb;
    if (i < 1000)                   *(u16x4*)&hsrcp[(size_t)i * 256 + d4] = nb;
    else if (i < 1024)              *(u16x4*)&hsrcp[(size_t)i * 256 + d4] = zz;
    if (i >= 1000 && i < 2000)      *(u16x4*)&hdstp[(size_t)(i - 1000) * 256 + d4] = nb;
    else if (i >= 2000 && i < 2024) *(u16x4*)&hdstp[(size_t)(i - 1000) * 256 + d4] = zz;
  } else if (b < 656) {
    int jb = b - 648;
    int cx = t & 31, ry = t >> 5;
    int j4 = jb * 128 + cx * 4;
    float4 s = {0.f, 0.f, 0.f, 0.f};
    if (j4 < 1000)
      for (int i = ry; i < 1000; i += 8) {
        float4 v = *(const float4*)&adj[(size_t)i * 2000 + 1000 + j4];
        s.x += v.x; s.y += v.y; s.z += v.z; s.w += v.w;
      }
    red4[ry][cx] = s;
    __syncthreads();
    if (ry == 0) {
      float4 tot = {0.f, 0.f, 0.f, 0.f};
      #pragma unroll
      for (int k = 0; k < 8; k++) {
        float4 v = red4[k][cx];
        tot.x += v.x; tot.y += v.y; tot.z += v.z; tot.w += v.w;
      }
      *(float4*)&degd[j4] = tot;
    }
  } else {
    int ib = b - 656;
    int r = t >> 3, c8 = t & 7;
    int i = ib * 32 + r;
    float s = 0.f;
    if (i < 1000)
      for (int k4 = c8 * 4; k4 < 1000; k4 += 32) {
        float4 v = *(const float4*)&adj[(size_t)i * 2000 + 1000 + k4];
        s += v.x + v.y + v.z + v.w;
      }
    redf[t] = s;
    __syncthreads();
    if (c8 == 0) {
      float tot = 0.f;
      #pragma unroll
      for (int k = 0; k < 8; k++) tot += redf[r * 8 + k];
      degs[i] = (i < 1000) ? tot : 0.f;
    }
  }
}

// ---------------- 32x32-tile bf16 MFMA core, 2-phase dbuf, XOR-swizzled LDS (proven R9) ----------------
__device__ __forceinline__ f32x4 gemm_core32(const u16* A, const u16* BT,
    int K, int lda, int ldbt, int brow, int bcol, u16* As, u16* Bs) {
  const int t = threadIdx.x;
  const int w = t >> 6, lane = t & 63;
  const int wr = w >> 1, wc = w & 1;
  const int r16 = lane & 15, kg = lane >> 4;
  const int row = t >> 3;
  const int csrc = (t & 7) ^ (row & 7);          // pre-swizzled source chunk
  f32x4 acc = {0.f, 0.f, 0.f, 0.f};
  const int nst = K >> 6;
  {
    const u16* ga = A + (size_t)(brow + row) * lda + csrc * 8;
    __builtin_amdgcn_global_load_lds(AS1C(ga), AS3(As + t * 8), 16, 0, 0);
    const u16* gb = BT + (size_t)(bcol + row) * ldbt + csrc * 8;
    __builtin_amdgcn_global_load_lds(AS1C(gb), AS3(Bs + t * 8), 16, 0, 0);
  }
  const int Ra = wr * 16 + r16;
  const int Rb = wc * 16 + r16;
  int cur = 0;
  for (int s = 0; s < nst; ++s) {
    __syncthreads();
    if (s + 1 < nst) {
      int k0 = (s + 1) << 6, nb = cur ^ 1;
      const u16* ga = A + (size_t)(brow + row) * lda + k0 + csrc * 8;
      __builtin_amdgcn_global_load_lds(AS1C(ga), AS3(As + nb * 2048 + t * 8), 16, 0, 0);
      const u16* gb = BT + (size_t)(bcol + row) * ldbt + k0 + csrc * 8;
      __builtin_amdgcn_global_load_lds(AS1C(gb), AS3(Bs + nb * 2048 + t * 8), 16, 0, 0);
    }
    const u16* Asc = As + cur * 2048;
    const u16* Bsc = Bs + cur * 2048;
    #pragma unroll
    for (int kk = 0; kk < 2; ++kk) {
      int g = kk * 4 + kg;
      bf16x8 af = *(const bf16x8*)&Asc[Ra * 64 + ((g ^ (Ra & 7)) * 8)];
      bf16x8 bf_ = *(const bf16x8*)&Bsc[Rb * 64 + ((g ^ (Rb & 7)) * 8)];
      acc = __builtin_amdgcn_mfma_f32_16x16x32_bf16(af, bf_, acc, 0, 0, 0);
    }
    cur ^= 1;
  }
  return acc;
}

// ---------------- mega1: symmetric S = A A^T (528, FIRST) + T1 = ne@ce^T (4096) ----------------
__global__ __launch_bounds__(256) void mega1(const u16* __restrict__ nep, const u16* __restrict__ cep,
    const u16* __restrict__ Ap, u16* __restrict__ T1, u16* __restrict__ Sp) {
  __shared__ u16 As[2 * 2048];
  __shared__ u16 Bs[2 * 2048];
  __shared__ u16 mir[32 * 33];
  int b = blockIdx.x;
  const int t = threadIdx.x;
  const int w = t >> 6, lane = t & 63;
  const int wr = w >> 1, wc = w & 1;
  const int r16 = lane & 15, kg = lane >> 4;
  if (b < 528) {                            // S jobs first (K=1024, long)
    int s = b;
    int bi = (int)((sqrtf(8.f * s + 1.f) - 1.f) * 0.5f);
    while (bi * (bi + 1) / 2 > s) bi--;
    while ((bi + 1) * (bi + 2) / 2 <= s) bi++;
    int bj = s - bi * (bi + 1) / 2;
    int brow = bi * 32, bcol = bj * 32;
    f32x4 acc = gemm_core32(Ap, Ap, 1024, 1024, 1024, brow, bcol, As, Bs);
    #pragma unroll
    for (int j = 0; j < 4; j++) {
      int lr = wr * 16 + kg * 4 + j, lc = wc * 16 + r16;
      u16 v = f2b(acc[j]);
      Sp[(size_t)(brow + lr) * 1024 + bcol + lc] = v;
      mir[lr * 33 + lc] = v;
    }
    __syncthreads();
    #pragma unroll
    for (int p = 0; p < 4; p++) {
      int idx = p * 256 + t, rr = idx >> 5, cc = idx & 31;
      Sp[(size_t)(bcol + rr) * 1024 + brow + cc] = mir[cc * 33 + rr];
    }
  } else {                                  // T1 jobs (K=128, short)
    int b2 = b - 528;
    int brow = (b2 >> 6) * 32, bcol = (b2 & 63) * 32;
    f32x4 acc = gemm_core32(nep, cep, 128, 128, 128, brow, bcol, As, Bs);
    #pragma unroll
    for (int j = 0; j < 4; j++) {
      int row = brow + wr * 16 + kg * 4 + j, col = bcol + wc * 16 + r16;
      T1[(size_t)row * 2048 + col] = f2b(acc[j]);
    }
  }
}

// ---------------- mega2: G gemm -> bf16 + norm partials (1024, first) + skipgram gather (391) ----
__global__ __launch_bounds__(256) void mega2(const u16* __restrict__ Sp, const u16* __restrict__ ATp,
    const u16* __restrict__ Ap, const float* __restrict__ degs, const float* __restrict__ degd,
    u16* __restrict__ Gns, u16* __restrict__ Gndt,
    float* __restrict__ rowp, float* __restrict__ colp,
    const u16* __restrict__ T1, const int* __restrict__ pu, const int* __restrict__ pv,
    const int* __restrict__ nv, float* __restrict__ partial) {
  __shared__ u16 As[2 * 2048];
  __shared__ u16 Bs[2 * 2048];
  __shared__ float gtile[32 * 33];
  __shared__ float red[256];
  int b = blockIdx.x;
  const int t = threadIdx.x;
  if (b >= 1024) {                          // skipgram gather
    int s = (b - 1024) * 256 + t;
    float loss = 0.f;
    if (s < BATCH) {
      const u16* trow = T1 + (size_t)pu[s] * 2048;
      const int* nvb = nv + (size_t)s * 5;
      float ap = b2f(trow[pv[s]]);
      ap = fminf(fmaxf(ap, -10.f), 10.f); loss = log1pf(expf(-ap));
      #pragma unroll
      for (int k = 0; k < 5; k++) {
        float a = b2f(trow[nvb[k]]);
        a = fminf(fmaxf(a, -10.f), 10.f);
        loss += log1pf(expf(a));
      }
    }
    red[t] = loss;
    __syncthreads();
    for (int off = 128; off > 0; off >>= 1) {
      if (t < off) red[t] += red[t + off];
      __syncthreads();
    }
    if (t == 0) partial[b - 1024] = red[0];
    return;
  }
  const int w = t >> 6, lane = t & 63;
  const int wr = w >> 1, wc = w & 1;
  const int r16 = lane & 15, kg = lane >> 4;
  int brow = (b >> 5) * 32, bcol = (b & 31) * 32;
  f32x4 acc = gemm_core32(Sp, ATp, 1024, 1024, 1024, brow, bcol, As, Bs);
  #pragma unroll
  for (int j = 0; j < 4; j++) {
    int lr = wr * 16 + kg * 4 + j, lc = wc * 16 + r16;
    int row = brow + lr, col = bcol + lc;
    float a = b2f(Ap[(size_t)row * 1024 + col]);
    float p2 = degs[row] * degd[col];
    float g = (p2 > 0.f) ? (acc[j] * a) / p2 : 0.f;
    Gns[(size_t)row * 1024 + col] = f2b(g);
    gtile[lr * 33 + lc] = g;
  }
  __syncthreads();
  // transposed bf16 write (coalesced)
  #pragma unroll
  for (int p = 0; p < 4; p++) {
    int idx = p * 256 + t, rr = idx >> 5, cc = idx & 31;
    Gndt[(size_t)(bcol + rr) * 1024 + brow + cc] = f2b(gtile[cc * 33 + rr]);
  }
  // deterministic norm partials: one writer per slot
  if (t < 32) {
    float s = 0.f;
    #pragma unroll
    for (int k = 0; k < 32; k++) { float g = gtile[t * 33 + k]; s += g * g; }
    rowp[(size_t)(bcol >> 5) * 1024 + brow + t] = s;
  } else if (t < 64) {
    int c = t - 32;
    float s = 0.f;
    #pragma unroll
    for (int k = 0; k < 32; k++) { float g = gtile[k * 33 + c]; s += g * g; }
    colp[(size_t)(brow >> 5) * 1024 + bcol + c] = s;
  }
}

// ---------------- hid = tanh((Gamma @ W1)/r + b1): 512 blocks (z = b>>8) ----------------
__global__ __launch_bounds__(256) void gemm_hid(const u16* __restrict__ Gns, const u16* __restrict__ W1Bt,
    const u16* __restrict__ Gndt, const u16* __restrict__ W1At,
    const float* __restrict__ rowp, const float* __restrict__ colp,
    const float* __restrict__ b1, u16* __restrict__ hid) {
  __shared__ u16 As[2 * 2048];
  __shared__ u16 Bs[2 * 2048];
  __shared__ float invr[32];
  const int t = threadIdx.x;
  const int w = t >> 6, lane = t & 63;
  const int wr = w >> 1, wc = w & 1;
  const int r16 = lane & 15, kg = lane >> 4;
  int b = blockIdx.x;
  int z = b >> 8, rem = b & 255;
  int brow = (rem & 31) * 32, bcol = (rem >> 5) * 32;
  // norm reconstruction (deterministic sum of 32 partials per row)
  if (t < 32) {
    const float* pp = z ? colp : rowp;
    float s = 0.f;
    #pragma unroll
    for (int k = 0; k < 32; k++) s += pp[(size_t)k * 1024 + brow + t];
    invr[t] = 1.0f / fmaxf(sqrtf(s), 1e-12f);
  }
  const u16* Au = z ? Gndt : Gns;
  const u16* Bu = z ? W1At : W1Bt;
  f32x4 acc = gemm_core32(Au, Bu, 1024, 1024, 1024, brow, bcol, As, Bs);
  #pragma unroll
  for (int j = 0; j < 4; j++) {
    int lr = wr * 16 + kg * 4 + j;
    int row = brow + lr;
    int col = bcol + wc * 16 + r16;
    hid[(size_t)((z << 10) + row) * 256 + col] = f2b(tanhf(acc[j] * invr[lr] + b1[col]));
  }
}

// ---------------- h[:,128:] = hid @ W2 + b2 (256 blocks) ----------------
__global__ __launch_bounds__(256) void gemm_w2(const u16* __restrict__ hid, const u16* __restrict__ w2t,
    const float* __restrict__ b2, u16* __restrict__ hsrcp, u16* __restrict__ hdstp) {
  __shared__ u16 As[2 * 2048];
  __shared__ u16 Bs[2 * 2048];
  const int t = threadIdx.x;
  const int w = t >> 6, lane = t & 63;
  const int wr = w >> 1, wc = w & 1;
  const int r16 = lane & 15, kg = lane >> 4;
  int b = blockIdx.x;
  int brow = (b >> 2) * 32, bcol = (b & 3) * 32;
  f32x4 acc = gemm_core32(hid, w2t, 256, 256, 256, brow, bcol, As, Bs);
  #pragma unroll
  for (int j = 0; j < 4; j++) {
    int row = brow + wr * 16 + kg * 4 + j;
    int col = bcol + wc * 16 + r16;
    u16 hv = f2b(acc[j] + b2[col]);
    if (row < 1024) hsrcp[(size_t)row * 256 + 128 + col] = hv;
    else            hdstp[(size_t)(row - 1024) * 256 + 128 + col] = hv;
  }
}

// ---------------- T2 = h_src @ h_dst^T (1024 blocks) ----------------
__global__ __launch_bounds__(256) void gemm_t2(const u16* __restrict__ hsrcp, const u16* __restrict__ hdstp,
    float* __restrict__ T2) {
  __shared__ u16 As[2 * 2048];
  __shared__ u16 Bs[2 * 2048];
  const int t = threadIdx.x;
  const int w = t >> 6, lane = t & 63;
  const int wr = w >> 1, wc = w & 1;
  const int r16 = lane & 15, kg = lane >> 4;
  int b = blockIdx.x;
  int brow = (b >> 5) * 32, bcol = (b & 31) * 32;
  f32x4 acc = gemm_core32(hsrcp, hdstp, 256, 256, 256, brow, bcol, As, Bs);
  #pragma unroll
  for (int j = 0; j < 4; j++) {
    int row = brow + wr * 16 + kg * 4 + j;
    int col = bcol + wc * 16 + r16;
    T2[(size_t)row * 1024 + col] = acc[j];
  }
}

// ---------------- edge gather from T2 + final loss reduce (block 1563) ----------------
__global__ __launch_bounds__(256) void edge_loss(const float* __restrict__ T2,
    const float* __restrict__ partial,
    const int* __restrict__ ps, const int* __restrict__ pd,
    const int* __restrict__ ns, const int* __restrict__ nd,
    float* __restrict__ out) {
  if (blockIdx.x == 1563) {
    __shared__ float red[256];
    float s = 0.f;
    for (int i = threadIdx.x; i < 391; i += 256) s += partial[i];
    red[threadIdx.x] = s;
    __syncthreads();
    for (int off = 128; off > 0; off >>= 1) {
      if (threadIdx.x < off) red[threadIdx.x] += red[threadIdx.x + off];
      __syncthreads();
    }
    if (threadIdx.x == 0) out[0] = red[0] / (float)BATCH;
    return;
  }
  int e = blockIdx.x * 256 + threadIdx.x;
  if (e >= 2 * EPE) return;
  int src, dst;
  if (e < EPE) { src = ps[e]; dst = pd[e]; }
  else         { src = ns[e - EPE]; dst = nd[e - EPE]; }
  out[1 + e] = T2[(size_t)src * 1024 + dst];
}

// ---------------- launch (7 kernels) ----------------
extern "C" void kernel_launch(void* const* d_in, const int* in_sizes, int n_in,
                              void* d_out, int out_size, void* d_ws, size_t ws_size,
                              hipStream_t stream) {
  const float* node_embed    = (const float*)d_in[0];
  const float* context_embed = (const float*)d_in[1];
  const float* adj           = (const float*)d_in[2];
  const float* W1            = (const float*)d_in[3];
  const float* b1            = (const float*)d_in[4];
  const float* W2            = (const float*)d_in[5];
  const float* b2            = (const float*)d_in[6];
  const int* pos_u   = (const int*)d_in[7];
  const int* pos_v   = (const int*)d_in[8];
  const int* neg_v   = (const int*)d_in[9];
  const int* pos_src = (const int*)d_in[10];
  const int* pos_dst = (const int*)d_in[11];
  const int* neg_src = (const int*)d_in[12];
  const int* neg_dst = (const int*)d_in[13];
  float* out = (float*)d_out;

  char* ws = (char*)d_ws;
  u16*   Ap    = (u16*)(ws + OFF_AP);
  u16*   ATp   = (u16*)(ws + OFF_ATP);
  u16*   Sp    = (u16*)(ws + OFF_SP);
  u16*   T1    = (u16*)(ws + OFF_T1);
  u16*   Gns   = (u16*)(ws + OFF_GNS);
  u16*   Gndt  = (u16*)(ws + OFF_GNDT);
  u16*   W1At  = (u16*)(ws + OFF_W1AT);
  u16*   W1Bt  = (u16*)(ws + OFF_W1BT);
  u16*   w2t   = (u16*)(ws + OFF_W2T);
  u16*   hid   = (u16*)(ws + OFF_HID);
  u16*   nep   = (u16*)(ws + OFF_NEP);
  u16*   cep   = (u16*)(ws + OFF_CEP);
  u16*   hsrcp = (u16*)(ws + OFF_HSRC);
  u16*   hdstp = (u16*)(ws + OFF_HDST);
  float* T2    = (float*)(ws + OFF_T2);
  float* rowp  = (float*)(ws + OFF_ROWP);
  float* colp  = (float*)(ws + OFF_COLP);
  float* degs  = (float*)(ws + OFF_DEGS);
  float* degd  = (float*)(ws + OFF_DEGD);
  float* part  = (float*)(ws + OFF_PART);

  // 1. packs + degrees
  prep<<<688, 256, 0, stream>>>(adj, W1, W2, node_embed, context_embed,
                                Ap, ATp, W1At, W1Bt, w2t, nep, cep, hsrcp, hdstp, degd, degs);
  // 2. S (528 long jobs first) + T1 (4096 short jobs)
  mega1<<<4624, 256, 0, stream>>>(nep, cep, Ap, T1, Sp);
  // 3. G gemm -> bf16 Gamma/Gamma^T + deterministic norm partials, + skipgram gather
  mega2<<<1415, 256, 0, stream>>>(Sp, ATp, Ap, degs, degd, Gns, Gndt, rowp, colp,
                                  T1, pos_u, pos_v, neg_v, part);
  // 4. hid = tanh((Gamma @ W1)/r + b1)   [normalization folded in]
  gemm_hid<<<512, 256, 0, stream>>>(Gns, W1Bt, Gndt, W1At, rowp, colp, b1, hid);
  // 5. h[:,128:] = hid @ W2 + b2
  gemm_w2<<<256, 256, 0, stream>>>(hid, w2t, b2, hsrcp, hdstp);
  // 6. T2 = h_src @ h_dst^T
  gemm_t2<<<1024, 256, 0, stream>>>(hsrcp, hdstp, T2);
  // 7. edge gathers + final loss reduce
  edge_loss<<<1564, 256, 0, stream>>>(T2, part, pos_src, pos_dst, neg_src, neg_dst, out);
}